// Round 9
// baseline (78.239 us; speedup 1.0000x reference)
//
#include <hip/hip_runtime.h>
#include <math.h>

#define NLEV   16
#define TSIZE  524288
#define TMASK  524287
#define NPIX   (1024*1024)
#define ENC_OFF_BYTES 32768

typedef __attribute__((ext_vector_type(8))) short s8v;
typedef __attribute__((ext_vector_type(4))) float f4v;

struct ResArr { float r[NLEV]; };
union Frag { unsigned int u[4]; s8v v; };

__device__ __forceinline__ unsigned short bf16_rn(float x) {
    unsigned int u = __builtin_bit_cast(unsigned int, x);
    u += 0x7fffu + ((u >> 16) & 1u);
    return (unsigned short)(u >> 16);
}
// truncating bf16 pack: one v_perm_b32 (values ~1e-4 vs 1e-2 threshold).
__device__ __forceinline__ unsigned int pk_bf16(float lo, float hi) {
    return __builtin_amdgcn_perm(__builtin_bit_cast(unsigned int, hi),
                                 __builtin_bit_cast(unsigned int, lo),
                                 0x07060302u);
}

// ws layout: [0..15] res f32. Then ushort region at ws+16:
//   w1t: W1^T bf16 [64][32]; w2t: W2^T k-permuted [64][64];
//   w3t: W3^T k-permuted row-replicated [16][64].
// At byte offset ENC_OFF_BYTES: enc buffer, u32 [NPIX][16] (64 MB), only used
// when ws_size permits (split path).
__global__ __launch_bounds__(256) void prep_kernel(
    const float* __restrict__ W1, const float* __restrict__ W2,
    const float* __restrict__ W3, float* __restrict__ ws, ResArr res)
{
    const int t = threadIdx.x;
    if (t < NLEV) ws[t] = res.r[t];
    unsigned short* w1t = (unsigned short*)(ws + 16);
    unsigned short* w2t = w1t + 64 * 32;
    unsigned short* w3t = w2t + 64 * 64;
    for (int i = t; i < 64 * 32; i += 256) {
        int n = i >> 5, k = i & 31;
        w1t[i] = bf16_rn(W1[k * 64 + n]);
    }
    for (int i = t; i < 64 * 64; i += 256) {
        int n2 = i >> 6, kp = i & 63;
        int klog = (kp & 32) | ((kp & 4) << 2) | ((kp & 24) >> 1) | (kp & 3);
        w2t[i] = bf16_rn(W2[klog * 64 + n2]);
    }
    for (int i = t; i < 16 * 64; i += 256) {
        int row = i >> 6, kp = i & 63;
        int klog = (kp & 32) | ((kp & 4) << 2) | ((kp & 24) >> 1) | (kp & 3);
        int ch = row & 3;
        w3t[i] = (ch < 3) ? bf16_rn(W3[klog * 3 + ch]) : (unsigned short)0;
    }
}

// ===================== split path: phase 1 (encode) =====================
// No MFMA/AGPR in this kernel -> the full register budget belongs to the
// gather pipeline. waves_per_eu(4,4) caps at 128 arch VGPRs (R7's spill came
// from 64 AGPRs inside this budget; here there are none).
// Writes enc[spatial_px][16 u32] in B-fragment word order (level pairs).
__global__ __launch_bounds__(256) __attribute__((amdgpu_waves_per_eu(4, 4)))
void ngp_enc_kernel(const float* __restrict__ tables,
                    const float* __restrict__ ws,
                    unsigned int* __restrict__ enc)
{
    const int tid  = threadIdx.x;
    const int lane = tid & 63;
    const int wv   = tid >> 6;
    const int c15  = lane & 15;
    const int g    = lane >> 4;
    const int xb   = blockIdx.x * 16;
    const int yb   = blockIdx.y * 16;

    const float4 rv = *(const float4*)(ws + g * 4);
    const float rr[4] = { rv.x, rv.y, rv.z, rv.w };
    const float xs = (float)(xb + c15) * (1.0f / 1024.0f);
    float yf[4];
    #pragma unroll
    for (int pt = 0; pt < 4; ++pt)
        yf[pt] = (float)(yb + wv * 4 + pt) * (1.0f / 1024.0f);

    const float2* __restrict__ tabg = (const float2*)tables + (size_t)(g * 4) * TSIZE;

    float2 fb[2][4][4];
    float  fxb[2];
    float  fyb[2][4];
    Frag   bfrag[4];

#define ENC_ISSUE(J, B) do {                                                  \
    const float r_   = rr[J];                                                 \
    const float sx_  = xs * r_;                                               \
    const float fx0_ = floorf(sx_);                                           \
    fxb[B] = sx_ - fx0_;                                                      \
    const unsigned int cx_  = (unsigned int)fx0_;                             \
    const unsigned int cx1_ = cx_ + 1u;                                       \
    const float2* __restrict__ tab_ = tabg + (size_t)(J) * TSIZE;             \
    _Pragma("unroll")                                                         \
    for (int pt_ = 0; pt_ < 4; ++pt_) {                                       \
        const float sy_  = yf[pt_] * r_;                                      \
        const float fy0_ = floorf(sy_);                                       \
        fyb[B][pt_] = sy_ - fy0_;                                             \
        const unsigned int cy_  = (unsigned int)fy0_;                         \
        const unsigned int hy0_ = cy_ * 2654435761u;                          \
        const unsigned int hy1_ = hy0_ + 2654435761u;                         \
        fb[B][pt_][0] = tab_[(cx_  ^ hy0_) & TMASK];                          \
        fb[B][pt_][1] = tab_[(cx1_ ^ hy0_) & TMASK];                          \
        fb[B][pt_][2] = tab_[(cx_  ^ hy1_) & TMASK];                          \
        fb[B][pt_][3] = tab_[(cx1_ ^ hy1_) & TMASK];                          \
    }                                                                         \
    asm volatile("" ::: "memory");                                            \
} while (0)

#define ENC_CONSUME(J, B) do {                                                \
    const float fx_ = fxb[B];                                                 \
    _Pragma("unroll")                                                         \
    for (int pt_ = 0; pt_ < 4; ++pt_) {                                       \
        const float fy_  = fyb[B][pt_];                                       \
        const float w00_ = (1.0f - fx_) * (1.0f - fy_);                       \
        const float w10_ = fx_          * (1.0f - fy_);                       \
        const float w01_ = (1.0f - fx_) * fy_;                                \
        const float w11_ = fx_          * fy_;                                \
        const float e0_ = w00_ * fb[B][pt_][0].x + w10_ * fb[B][pt_][1].x     \
                        + w01_ * fb[B][pt_][2].x + w11_ * fb[B][pt_][3].x;    \
        const float e1_ = w00_ * fb[B][pt_][0].y + w10_ * fb[B][pt_][1].y     \
                        + w01_ * fb[B][pt_][2].y + w11_ * fb[B][pt_][3].y;    \
        bfrag[pt_].u[J] = pk_bf16(e0_, e1_);                                  \
    }                                                                         \
} while (0)

    ENC_ISSUE(0, 0);
    ENC_ISSUE(1, 1);
    ENC_CONSUME(0, 0);
    ENC_ISSUE(2, 0);
    ENC_CONSUME(1, 1);
    ENC_ISSUE(3, 1);
    ENC_CONSUME(2, 0);
    ENC_CONSUME(3, 1);

#undef ENC_ISSUE
#undef ENC_CONSUME

    // store: per pt one dwordx4 (words g*4..g*4+3 of spatial pixel row);
    // a wave's 64 lanes cover a contiguous 1 KiB range per pt.
    #pragma unroll
    for (int pt = 0; pt < 4; ++pt) {
        const int row = ((yb + wv * 4 + pt) << 10) + xb + c15;
        *(uint4*)(enc + (size_t)row * 16 + g * 4) = *(const uint4*)&bfrag[pt];
    }
}

// ===================== split path: phase 2 (MLP) =====================
// Pure streaming GEMM: wave w handles 64 consecutive pixels. B-fragments load
// coalesced from enc; all three layers on MFMA with lane-local activation
// hand-off (k-permuted weights); phase-split accumulators (16 AGPRs peak).
__global__ __launch_bounds__(256) void ngp_mlp_kernel(
    const unsigned int* __restrict__ enc,
    const float* __restrict__ b1, const float* __restrict__ b2,
    const float* __restrict__ b3,
    const float* __restrict__ ws, float* __restrict__ out)
{
    const int tid  = threadIdx.x;
    const int lane = tid & 63;
    const int wv   = tid >> 6;
    const int c15  = lane & 15;
    const int g    = lane >> 4;
    const int base = (blockIdx.x * 4 + wv) * 64;

    Frag bfrag[4];
    #pragma unroll
    for (int pt = 0; pt < 4; ++pt)
        *(uint4*)&bfrag[pt] =
            *(const uint4*)(enc + (size_t)(base + pt * 16 + c15) * 16 + g * 4);

    const unsigned short* __restrict__ w1t = (const unsigned short*)(ws + 16);
    const unsigned short* __restrict__ w2t = w1t + 64 * 32;
    const unsigned short* __restrict__ w3t = w2t + 64 * 64;

    // layer 1
    unsigned int hp[4][4][2];
    #pragma unroll
    for (int mt = 0; mt < 4; ++mt) {
        Frag afr;
        afr.v = *(const s8v*)(w1t + (mt * 16 + c15) * 32 + g * 8);
        const float4 bb = *(const float4*)(b1 + mt * 16 + g * 4);
        #pragma unroll
        for (int pt = 0; pt < 4; ++pt) {
            f4v acc = (f4v){0.f, 0.f, 0.f, 0.f};
            acc = __builtin_amdgcn_mfma_f32_16x16x32_bf16(
                afr.v, bfrag[pt].v, acc, 0, 0, 0);
            const float v0 = fmaxf(acc[0] + bb.x, 0.0f);
            const float v1 = fmaxf(acc[1] + bb.y, 0.0f);
            const float v2 = fmaxf(acc[2] + bb.z, 0.0f);
            const float v3 = fmaxf(acc[3] + bb.w, 0.0f);
            hp[mt][pt][0] = pk_bf16(v0, v1);
            hp[mt][pt][1] = pk_bf16(v2, v3);
        }
    }

    // layer 2 (per-mt accumulator split)
    unsigned int hq[4][4][2];
    #pragma unroll
    for (int mt = 0; mt < 4; ++mt) {
        const float4 bb2 = *(const float4*)(b2 + mt * 16 + g * 4);
        f4v acc[4];
        #pragma unroll
        for (int pt = 0; pt < 4; ++pt) acc[pt] = (f4v){0.f, 0.f, 0.f, 0.f};
        #pragma unroll
        for (int st = 0; st < 2; ++st) {
            Frag a2, bf2[4];
            a2.v = *(const s8v*)(w2t + (mt * 16 + c15) * 64 + st * 32 + g * 8);
            #pragma unroll
            for (int pt = 0; pt < 4; ++pt) {
                bf2[pt].u[0] = hp[2 * st + 0][pt][0];
                bf2[pt].u[1] = hp[2 * st + 0][pt][1];
                bf2[pt].u[2] = hp[2 * st + 1][pt][0];
                bf2[pt].u[3] = hp[2 * st + 1][pt][1];
            }
            #pragma unroll
            for (int pt = 0; pt < 4; ++pt)
                acc[pt] = __builtin_amdgcn_mfma_f32_16x16x32_bf16(
                    a2.v, bf2[pt].v, acc[pt], 0, 0, 0);
        }
        #pragma unroll
        for (int pt = 0; pt < 4; ++pt) {
            const float v0 = fmaxf(acc[pt][0] + bb2.x, 0.0f);
            const float v1 = fmaxf(acc[pt][1] + bb2.y, 0.0f);
            const float v2 = fmaxf(acc[pt][2] + bb2.z, 0.0f);
            const float v3 = fmaxf(acc[pt][3] + bb2.w, 0.0f);
            hq[mt][pt][0] = pk_bf16(v0, v1);
            hq[mt][pt][1] = pk_bf16(v2, v3);
        }
    }

    // layer 3 on MFMA (row-replicated W3: reg r = channel r on every lane)
    f4v acc3[4];
    #pragma unroll
    for (int pt = 0; pt < 4; ++pt) acc3[pt] = (f4v){0.f, 0.f, 0.f, 0.f};
    #pragma unroll
    for (int st = 0; st < 2; ++st) {
        Frag a3, bf3[4];
        a3.v = *(const s8v*)(w3t + c15 * 64 + st * 32 + g * 8);
        #pragma unroll
        for (int pt = 0; pt < 4; ++pt) {
            bf3[pt].u[0] = hq[2 * st + 0][pt][0];
            bf3[pt].u[1] = hq[2 * st + 0][pt][1];
            bf3[pt].u[2] = hq[2 * st + 1][pt][0];
            bf3[pt].u[3] = hq[2 * st + 1][pt][1];
        }
        #pragma unroll
        for (int pt = 0; pt < 4; ++pt)
            acc3[pt] = __builtin_amdgcn_mfma_f32_16x16x32_bf16(
                a3.v, bf3[pt].v, acc3[pt], 0, 0, 0);
    }

    float ov[3];
    #pragma unroll
    for (int c = 0; c < 3; ++c) {
        float v = acc3[0][c];
        v = (g == 1) ? acc3[1][c] : v;
        v = (g == 2) ? acc3[2][c] : v;
        v = (g == 3) ? acc3[3][c] : v;
        ov[c] = v + b3[c];
    }
    const int pix = base + g * 16 + c15;
    out[0 * NPIX + pix] = 1.0f / (1.0f + __expf(-ov[0]));
    out[1 * NPIX + pix] = 1.0f / (1.0f + __expf(-ov[1]));
    out[2 * NPIX + pix] = 1.0f / (1.0f + __expf(-ov[2]));
}

// ===================== fallback: R8 fused kernel (verbatim) =====================
__global__ __launch_bounds__(256) void ngp_fused_kernel(
    const float* __restrict__ tables,
    const float* __restrict__ b1, const float* __restrict__ b2,
    const float* __restrict__ b3,
    const float* __restrict__ ws, float* __restrict__ out)
{
    const int tid  = threadIdx.x;
    const int lane = tid & 63;
    const int wv   = tid >> 6;
    const int c15  = lane & 15;
    const int g    = lane >> 4;
    const int xb   = blockIdx.x * 16;
    const int yb   = blockIdx.y * 16;

    const float4 rv = *(const float4*)(ws + g * 4);
    const float rr[4] = { rv.x, rv.y, rv.z, rv.w };
    const float xs = (float)(xb + c15) * (1.0f / 1024.0f);
    float yf[4];
    #pragma unroll
    for (int pt = 0; pt < 4; ++pt)
        yf[pt] = (float)(yb + wv * 4 + pt) * (1.0f / 1024.0f);

    const float2* __restrict__ tabg = (const float2*)tables + (size_t)(g * 4) * TSIZE;

    float2 fb[2][4][4];
    float  fxb[2];
    float  fyb[2][4];
    Frag   bfrag[4];

#define NGP_ISSUE(J, B) do {                                                  \
    const float r_   = rr[J];                                                 \
    const float sx_  = xs * r_;                                               \
    const float fx0_ = floorf(sx_);                                           \
    fxb[B] = sx_ - fx0_;                                                      \
    const unsigned int cx_  = (unsigned int)fx0_;                             \
    const unsigned int cx1_ = cx_ + 1u;                                       \
    const float2* __restrict__ tab_ = tabg + (size_t)(J) * TSIZE;             \
    _Pragma("unroll")                                                         \
    for (int pt_ = 0; pt_ < 4; ++pt_) {                                       \
        const float sy_  = yf[pt_] * r_;                                      \
        const float fy0_ = floorf(sy_);                                       \
        fyb[B][pt_] = sy_ - fy0_;                                             \
        const unsigned int cy_  = (unsigned int)fy0_;                         \
        const unsigned int hy0_ = cy_ * 2654435761u;                          \
        const unsigned int hy1_ = hy0_ + 2654435761u;                         \
        fb[B][pt_][0] = tab_[(cx_  ^ hy0_) & TMASK];                          \
        fb[B][pt_][1] = tab_[(cx1_ ^ hy0_) & TMASK];                          \
        fb[B][pt_][2] = tab_[(cx_  ^ hy1_) & TMASK];                          \
        fb[B][pt_][3] = tab_[(cx1_ ^ hy1_) & TMASK];                          \
    }                                                                         \
    asm volatile("" ::: "memory");                                            \
} while (0)

#define NGP_CONSUME(J, B) do {                                                \
    const float fx_ = fxb[B];                                                 \
    _Pragma("unroll")                                                         \
    for (int pt_ = 0; pt_ < 4; ++pt_) {                                       \
        const float fy_  = fyb[B][pt_];                                       \
        const float w00_ = (1.0f - fx_) * (1.0f - fy_);                       \
        const float w10_ = fx_          * (1.0f - fy_);                       \
        const float w01_ = (1.0f - fx_) * fy_;                                \
        const float w11_ = fx_          * fy_;                                \
        const float e0_ = w00_ * fb[B][pt_][0].x + w10_ * fb[B][pt_][1].x     \
                        + w01_ * fb[B][pt_][2].x + w11_ * fb[B][pt_][3].x;    \
        const float e1_ = w00_ * fb[B][pt_][0].y + w10_ * fb[B][pt_][1].y     \
                        + w01_ * fb[B][pt_][2].y + w11_ * fb[B][pt_][3].y;    \
        bfrag[pt_].u[J] = pk_bf16(e0_, e1_);                                  \
    }                                                                         \
} while (0)

    const unsigned short* __restrict__ w1t = (const unsigned short*)(ws + 16);
    const unsigned short* __restrict__ w2t = w1t + 64 * 32;
    const unsigned short* __restrict__ w3t = w2t + 64 * 64;
    Frag afr[4];

    NGP_ISSUE(0, 0);
    NGP_ISSUE(1, 1);
    NGP_CONSUME(0, 0);
    NGP_ISSUE(2, 0);
    NGP_CONSUME(1, 1);
    NGP_ISSUE(3, 1);
    #pragma unroll
    for (int mt = 0; mt < 4; ++mt)
        afr[mt].v = *(const s8v*)(w1t + (mt * 16 + c15) * 32 + g * 8);
    asm volatile("" ::: "memory");
    NGP_CONSUME(2, 0);
    NGP_CONSUME(3, 1);

#undef NGP_ISSUE
#undef NGP_CONSUME

    unsigned int hp[4][4][2];
    #pragma unroll
    for (int mt = 0; mt < 4; ++mt) {
        const float4 bb = *(const float4*)(b1 + mt * 16 + g * 4);
        #pragma unroll
        for (int pt = 0; pt < 4; ++pt) {
            f4v acc = (f4v){0.f, 0.f, 0.f, 0.f};
            acc = __builtin_amdgcn_mfma_f32_16x16x32_bf16(
                afr[mt].v, bfrag[pt].v, acc, 0, 0, 0);
            const float v0 = fmaxf(acc[0] + bb.x, 0.0f);
            const float v1 = fmaxf(acc[1] + bb.y, 0.0f);
            const float v2 = fmaxf(acc[2] + bb.z, 0.0f);
            const float v3 = fmaxf(acc[3] + bb.w, 0.0f);
            hp[mt][pt][0] = pk_bf16(v0, v1);
            hp[mt][pt][1] = pk_bf16(v2, v3);
        }
    }

    unsigned int hq[4][4][2];
    #pragma unroll
    for (int mt = 0; mt < 4; ++mt) {
        const float4 bb2 = *(const float4*)(b2 + mt * 16 + g * 4);
        f4v acc[4];
        #pragma unroll
        for (int pt = 0; pt < 4; ++pt) acc[pt] = (f4v){0.f, 0.f, 0.f, 0.f};
        #pragma unroll
        for (int st = 0; st < 2; ++st) {
            Frag a2, bf2[4];
            a2.v = *(const s8v*)(w2t + (mt * 16 + c15) * 64 + st * 32 + g * 8);
            #pragma unroll
            for (int pt = 0; pt < 4; ++pt) {
                bf2[pt].u[0] = hp[2 * st + 0][pt][0];
                bf2[pt].u[1] = hp[2 * st + 0][pt][1];
                bf2[pt].u[2] = hp[2 * st + 1][pt][0];
                bf2[pt].u[3] = hp[2 * st + 1][pt][1];
            }
            #pragma unroll
            for (int pt = 0; pt < 4; ++pt)
                acc[pt] = __builtin_amdgcn_mfma_f32_16x16x32_bf16(
                    a2.v, bf2[pt].v, acc[pt], 0, 0, 0);
        }
        #pragma unroll
        for (int pt = 0; pt < 4; ++pt) {
            const float v0 = fmaxf(acc[pt][0] + bb2.x, 0.0f);
            const float v1 = fmaxf(acc[pt][1] + bb2.y, 0.0f);
            const float v2 = fmaxf(acc[pt][2] + bb2.z, 0.0f);
            const float v3 = fmaxf(acc[pt][3] + bb2.w, 0.0f);
            hq[mt][pt][0] = pk_bf16(v0, v1);
            hq[mt][pt][1] = pk_bf16(v2, v3);
        }
    }

    f4v acc3[4];
    #pragma unroll
    for (int pt = 0; pt < 4; ++pt) acc3[pt] = (f4v){0.f, 0.f, 0.f, 0.f};
    #pragma unroll
    for (int st = 0; st < 2; ++st) {
        Frag a3, bf3[4];
        a3.v = *(const s8v*)(w3t + c15 * 64 + st * 32 + g * 8);
        #pragma unroll
        for (int pt = 0; pt < 4; ++pt) {
            bf3[pt].u[0] = hq[2 * st + 0][pt][0];
            bf3[pt].u[1] = hq[2 * st + 0][pt][1];
            bf3[pt].u[2] = hq[2 * st + 1][pt][0];
            bf3[pt].u[3] = hq[2 * st + 1][pt][1];
        }
        #pragma unroll
        for (int pt = 0; pt < 4; ++pt)
            acc3[pt] = __builtin_amdgcn_mfma_f32_16x16x32_bf16(
                a3.v, bf3[pt].v, acc3[pt], 0, 0, 0);
    }

    float ov[3];
    #pragma unroll
    for (int c = 0; c < 3; ++c) {
        float v = acc3[0][c];
        v = (g == 1) ? acc3[1][c] : v;
        v = (g == 2) ? acc3[2][c] : v;
        v = (g == 3) ? acc3[3][c] : v;
        ov[c] = v + b3[c];
    }
    const int pix = ((yb + wv * 4 + g) << 10) + xb + c15;
    out[0 * NPIX + pix] = 1.0f / (1.0f + __expf(-ov[0]));
    out[1 * NPIX + pix] = 1.0f / (1.0f + __expf(-ov[1]));
    out[2 * NPIX + pix] = 1.0f / (1.0f + __expf(-ov[2]));
}

extern "C" void kernel_launch(void* const* d_in, const int* in_sizes, int n_in,
                              void* d_out, int out_size, void* d_ws, size_t ws_size,
                              hipStream_t stream) {
    const float* tables = (const float*)d_in[0];
    const float* W1     = (const float*)d_in[1];
    const float* b1     = (const float*)d_in[2];
    const float* W2     = (const float*)d_in[3];
    const float* b2     = (const float*)d_in[4];
    const float* W3     = (const float*)d_in[5];
    const float* b3     = (const float*)d_in[6];
    float* out          = (float*)d_out;
    float* ws           = (float*)d_ws;

    ResArr res;
    const double growth = exp((log(1024.0) - log(16.0)) / 15.0);
    for (int l = 0; l < NLEV; ++l)
        res.r[l] = (float)floor(16.0 * pow(growth, (double)l));

    hipLaunchKernelGGL(prep_kernel, dim3(1), dim3(256), 0, stream, W1, W2, W3, ws, res);

    const size_t need = (size_t)ENC_OFF_BYTES + (size_t)NPIX * 64;
    if (ws_size >= need) {
        unsigned int* enc = (unsigned int*)((char*)d_ws + ENC_OFF_BYTES);
        hipLaunchKernelGGL(ngp_enc_kernel, dim3(64, 64), dim3(256), 0, stream,
                           tables, ws, enc);
        hipLaunchKernelGGL(ngp_mlp_kernel, dim3(4096), dim3(256), 0, stream,
                           enc, b1, b2, b3, ws, out);
    } else {
        hipLaunchKernelGGL(ngp_fused_kernel, dim3(64, 64), dim3(256), 0, stream,
                           tables, b1, b2, b3, ws, out);
    }
}